// Round 12
// baseline (244.108 us; speedup 1.0000x reference)
//
#include <hip/hip_runtime.h>
#include <hip/hip_bf16.h>

// Shapes fixed by setup_inputs(): B=2, C=128, H=256, W=448, stride=1.
#define BB 2
#define CC 128
#define HH 256
#define WW 448
#define KK 49
#define HWSZ (HH * WW)
#define PW 456  // padded width of wt: px = x+4, x in [-4, 452)

#define WT_BYTES ((size_t)BB * HH * PW * CC * 2)      // 59,768,832
#define TWT_BYTES ((size_t)BB * HH * WW * CC * 2)     // 58,720,256
#define WS_NEED (WT_BYTES + TWT_BYTES)

typedef __attribute__((ext_vector_type(8))) short bf16x8;
typedef __attribute__((ext_vector_type(4))) float f32x4;
typedef __attribute__((ext_vector_type(8))) unsigned short u16x8;

static __device__ __forceinline__ short f2bf(float v) {
  __hip_bfloat16 h = __float2bfloat16(v);
  return *reinterpret_cast<short*>(&h);
}
static __device__ __forceinline__ float bf2f(unsigned short u) {
  unsigned int x = ((unsigned int)u) << 16;
  return __uint_as_float(x);
}

typedef const __attribute__((address_space(1))) unsigned int* as1_u32p;
typedef __attribute__((address_space(3))) unsigned int* as3_u32p;
static __device__ __forceinline__ void gload_lds16(const void* g, void* l) {
  __builtin_amdgcn_global_load_lds((as1_u32p)g, (as3_u32p)l, 16, 0, 0);
}

// ---------------- Kernel 0: zero the x-padding borders of wt ----------------
__global__ __launch_bounds__(256) void border_kernel(__hip_bfloat16* wt) {
  int i = blockIdx.x * 256 + threadIdx.x;  // 65536
  int by = i >> 7;
  int r = i & 127;
  int ps = r >> 4;
  int c16 = r & 15;
  int px = (ps < 4) ? ps : (448 + ps);
  u16x8 z = {0, 0, 0, 0, 0, 0, 0, 0};
  *(u16x8*)((char*)wt + ((size_t)((size_t)by * PW + px) * CC + c16 * 8) * 2) = z;
}

// ---------------- Kernel T: transpose tenTwo [c][p] f32 -> two_t [p][c] bf16
__global__ __launch_bounds__(256) void transpose_kernel(
    const float* __restrict__ two, __hip_bfloat16* __restrict__ two_t) {
  __shared__ float lds[128 * 33];
  int bid = blockIdx.x;            // BB * 3584
  int b = bid / (HWSZ / 32);
  int tile = bid - b * (HWSZ / 32);
  int P0 = tile * 32;

  const float* src = two + (size_t)b * CC * HWSZ + P0;
  int t = threadIdx.x;
  int bc = t >> 3;   // 0..31
  int f = t & 7;     // 0..7
#pragma unroll
  for (int k = 0; k < 4; ++k) {
    int c = bc + k * 32;
    float4 v = *(const float4*)(src + (size_t)c * HWSZ + f * 4);
    float* d = &lds[c * 33 + f * 4];
    d[0] = v.x; d[1] = v.y; d[2] = v.z; d[3] = v.w;
  }
  __syncthreads();

  int q = t & 7;     // c-chunk of 16
  int pl = t >> 3;   // 0..31 pixel
  int cs = q * 16;
  u16x8 pk0, pk1;
#pragma unroll
  for (int j = 0; j < 8; ++j)
    pk0[j] = (unsigned short)f2bf(lds[(cs + j) * 33 + pl]);
#pragma unroll
  for (int j = 0; j < 8; ++j)
    pk1[j] = (unsigned short)f2bf(lds[(cs + 8 + j) * 33 + pl]);
  char* dst = (char*)two_t + ((size_t)((size_t)b * HWSZ + P0 + pl) * CC + cs) * 2;
  *(u16x8*)dst = pk0;
  *(u16x8*)(dst + 16) = pk1;
}

// ---------------- Kernel 1 (fast): gather from two_t [p][c] bf16 -----------
// 1024 threads (64 px-groups x 16 chunks), 512 blocks (one per row) ->
// up to 32 waves/CU for latency hiding. Reads/stores 256B dense per group.
__global__ __launch_bounds__(1024) void warp_fast(
    const __hip_bfloat16* __restrict__ two_t, const float* __restrict__ flow,
    __hip_bfloat16* __restrict__ wt) {
  int wg = (blockIdx.x & 7) * 64 + (blockIdx.x >> 3);  // bijective, 512
  int b = wg >> 8;
  int y = wg & 255;
  int pg = threadIdx.x >> 4;  // 0..63 pixel group
  int cw = threadIdx.x & 15;  // 16B channel chunk

  const char* tb = (const char*)two_t + (size_t)b * HWSZ * (CC * 2);
  char* wb = (char*)wt + ((size_t)(b * HH + y) * PW + 4) * (CC * 2);
  const float* fxp = flow + (size_t)(b * 2 + 0) * HWSZ + y * WW;
  const float* fyp = flow + (size_t)(b * 2 + 1) * HWSZ + y * WW;

#pragma unroll 2
  for (int it = 0; it < 7; ++it) {
    int x = it * 64 + pg;

    float fx = fxp[x] * 2.5f;
    float fy = fyp[x] * 2.5f;
    float px = (float)x + fx;
    float py = (float)y + fy;
    float x0f = floorf(px), y0f = floorf(py);
    int x0 = (int)x0f, y0 = (int)y0f;
    int x1 = x0 + 1, y1 = y0 + 1;
    float wx1 = px - x0f, wx0 = 1.0f - wx1;
    float wy1 = py - y0f, wy0 = 1.0f - wy1;
    bool vx0 = (x0 >= 0) && (x0 < WW);
    bool vx1 = (x1 >= 0) && (x1 < WW);
    bool vy0 = (y0 >= 0) && (y0 < HH);
    bool vy1 = (y1 >= 0) && (y1 < HH);
    float w00 = (vx0 && vy0) ? wx0 * wy0 : 0.0f;
    float w01 = (vx1 && vy0) ? wx1 * wy0 : 0.0f;
    float w10 = (vx0 && vy1) ? wx0 * wy1 : 0.0f;
    float w11 = (vx1 && vy1) ? wx1 * wy1 : 0.0f;
    int cx0 = min(max(x0, 0), WW - 1);
    int cx1 = min(max(x1, 0), WW - 1);
    int cy0 = min(max(y0, 0), HH - 1);
    int cy1 = min(max(y1, 0), HH - 1);

    u16x8 a = *(const u16x8*)(tb + ((size_t)cy0 * WW + cx0) * 256 + cw * 16);
    u16x8 bb_ = *(const u16x8*)(tb + ((size_t)cy0 * WW + cx1) * 256 + cw * 16);
    u16x8 c = *(const u16x8*)(tb + ((size_t)cy1 * WW + cx0) * 256 + cw * 16);
    u16x8 d = *(const u16x8*)(tb + ((size_t)cy1 * WW + cx1) * 256 + cw * 16);

    u16x8 pk;
#pragma unroll
    for (int e = 0; e < 8; ++e) {
      float v = w00 * bf2f((unsigned short)a[e]) +
                w01 * bf2f((unsigned short)bb_[e]) +
                w10 * bf2f((unsigned short)c[e]) +
                w11 * bf2f((unsigned short)d[e]);
      pk[e] = (unsigned short)f2bf(v);
    }
    *(u16x8*)(wb + (size_t)x * 256 + cw * 16) = pk;
  }
}

// ---------------- Kernel 1 (fallback): gather f32 planes directly -----------
__global__ __launch_bounds__(256) void warp_fallback(
    const float* __restrict__ two, const float* __restrict__ flow,
    __hip_bfloat16* __restrict__ wt) {
  int idx = blockIdx.x * 256 + threadIdx.x;
  if (idx >= BB * HWSZ) return;
  int x = idx % WW;
  int y = (idx / WW) % HH;
  int b = idx / HWSZ;

  float fx = flow[(b * 2 + 0) * HWSZ + y * WW + x] * 2.5f;
  float fy = flow[(b * 2 + 1) * HWSZ + y * WW + x] * 2.5f;
  float px = (float)x + fx;
  float py = (float)y + fy;
  float x0f = floorf(px), y0f = floorf(py);
  int x0 = (int)x0f, y0 = (int)y0f;
  int x1 = x0 + 1, y1 = y0 + 1;
  float wx1 = px - x0f, wx0 = 1.0f - wx1;
  float wy1 = py - y0f, wy0 = 1.0f - wy1;
  bool vx0 = (x0 >= 0) && (x0 < WW);
  bool vx1 = (x1 >= 0) && (x1 < WW);
  bool vy0 = (y0 >= 0) && (y0 < HH);
  bool vy1 = (y1 >= 0) && (y1 < HH);
  float w00 = (vx0 && vy0) ? wx0 * wy0 : 0.0f;
  float w01 = (vx1 && vy0) ? wx1 * wy0 : 0.0f;
  float w10 = (vx0 && vy1) ? wx0 * wy1 : 0.0f;
  float w11 = (vx1 && vy1) ? wx1 * wy1 : 0.0f;
  int cx0 = min(max(x0, 0), WW - 1);
  int cx1 = min(max(x1, 0), WW - 1);
  int cy0 = min(max(y0, 0), HH - 1);
  int cy1 = min(max(y1, 0), HH - 1);
  int o00 = cy0 * WW + cx0;
  int o01 = cy0 * WW + cx1;
  int o10 = cy1 * WW + cx0;
  int o11 = cy1 * WW + cx1;

  const float* p = two + (size_t)b * CC * HWSZ;
  char* wo = (char*)wt + ((size_t)((size_t)(b * HH + y) * PW) + x + 4) * CC * 2;
#pragma unroll 4
  for (int j = 0; j < 16; ++j) {
    u16x8 pk;
#pragma unroll
    for (int jj = 0; jj < 8; ++jj) {
      int c = j * 8 + jj;
      const float* pc = p + (size_t)c * HWSZ;
      float v = w00 * pc[o00] + w01 * pc[o01] + w10 * pc[o10] + w11 * pc[o11];
      pk[jj] = (unsigned short)f2bf(v);
    }
    *(u16x8*)(wo + j * 16) = pk;
  }
}

// ---------------- Kernel 2: persistent double-buffered MFMA correlation -----
// 256 blocks (1/CU, LDS-limited), 7 tiles each, 2x78.8KB LDS buffers.
// Per tile: [barrier] -> issue stage(i+1)+A(i+1) -> compute(i) -> epilogue(i).
// Next tile's loads are always in flight across the phase walls.
#define YTB 8
#define NROWS 14               // YTB + 6
#define NPOS 22
#define ROWCH (NPOS * 16)      // 352 16B-chunks per row
#define CHUNKS (NROWS * ROWCH) // 4928 chunks = 78,848 B

__global__ __launch_bounds__(512) void corr_kernel(
    const float* __restrict__ one, const __hip_bfloat16* __restrict__ wt,
    float* __restrict__ out) {
  __shared__ uint4 ldsb[2][CHUNKS];  // 157,696 B

  int bid = blockIdx.x;  // 0..255
  int tid = threadIdx.x;
  int w = tid >> 6;   // wave 0..7
  int l = tid & 63;
  int lp = l & 15;
  int lg = l >> 4;

  // ---- tile-invariant staging descriptors (registers, const-indexed) ------
  int srow[10], soff[10];
#pragma unroll
  for (int k = 0; k < 10; ++k) {
    int ci = tid + k * 512;
    int row = ci / ROWCH;
    int r2 = ci - row * ROWCH;
    int p = r2 >> 4;
    int cw = r2 & 15;
    int cwS = cw ^ (p & 7);  // pre-swizzled SOURCE, linear DEST
    srow[k] = row;
    soff[k] = row * (PW * CC * 2) + p * 256 + cwS * 16;
  }
  int p1 = (lp + 16 < 21) ? (lp + 16) : 21;
  int cosw0[4], cosw1[4];
#pragma unroll
  for (int t = 0; t < 4; ++t) {
    int co = t * 64 + lg * 16;
    cosw0[t] = co ^ ((lp & 7) << 4);
    cosw1[t] = co ^ ((p1 & 7) << 4);
  }

  // ---- per-tile helpers ----------------------------------------------------
  uint4 zz = {0, 0, 0, 0};
  auto stage = [&](int t, uint4* buf) {
    int b = t / 896;
    int rem = t - b * 896;
    int xt = rem >> 5;
    int yt = rem & 31;
    int ybase = yt * YTB;
    int X0 = xt * 16;
    const char* wbase =
        (const char*)wt + (((size_t)(b * HH)) * PW + X0 + 1) * (CC * 2);
    const char* gb = wbase + (ptrdiff_t)(ybase - 3) * (PW * CC * 2);
    if (yt == 0) {  // rows 0..2 OOB -> zero-fill (wave-uniform branch)
#pragma unroll
      for (int k2 = 0; k2 < 3; ++k2) {
        int ci = tid + k2 * 512;
        if (ci < 3 * ROWCH) buf[ci] = zz;
      }
    } else if (yt == 31) {  // rows 11..13 OOB
#pragma unroll
      for (int k2 = 0; k2 < 3; ++k2) {
        int ci = tid + k2 * 512;
        if (ci < 3 * ROWCH) buf[11 * ROWCH + ci] = zz;
      }
    }
#pragma unroll
    for (int k = 0; k < 10; ++k) {
      bool inb = (k < 9) || (tid < (CHUNKS - 9 * 512));  // tail = 5 full waves
      unsigned yy = (unsigned)(ybase - 3 + srow[k]);
      if (inb && yy < HH)
        gload_lds16(gb + soff[k],
                    (char*)buf + (size_t)(k * 512 + (tid & ~63)) * 16);
    }
  };
  auto aload = [&](int t, float* af) {
    int b = t / 896;
    int rem = t - b * 896;
    int xt = rem >> 5;
    int yt = rem & 31;
    int y = yt * YTB + w;
    int X0 = xt * 16;
    const float* Ab = one + ((size_t)(b * CC) * HH + y) * WW + X0 + lp;
#pragma unroll
    for (int tt = 0; tt < 4; ++tt)
#pragma unroll
      for (int j = 0; j < 8; ++j)
        af[tt * 8 + j] = Ab[(size_t)(tt * 32 + lg * 8 + j) * HWSZ];
  };

  // ---- prologue: tile 0 ----------------------------------------------------
  float af0[32], af1[32];
  stage(bid, ldsb[0]);
  aload(bid, af0);

#pragma unroll
  for (int i = 0; i < 7; ++i) {
    const int cur = i & 1;
    int t = i * 256 + bid;
    int b = t / 896;
    int rem = t - b * 896;
    int xt = rem >> 5;
    int yt = rem & 31;
    int ybase = yt * YTB;
    int X0 = xt * 16;

    __syncthreads();  // buf[cur] staged/zeroed ready; af for tile i loaded

    if (i + 1 < 7) {  // issue next tile's loads (stay in flight over compute)
      stage((i + 1) * 256 + bid, ldsb[cur ^ 1]);
      if ((i + 1) & 1) aload((i + 1) * 256 + bid, af1);
      else             aload((i + 1) * 256 + bid, af0);
    }

    // ---- compute tile i ----------------------------------------------------
    float* afc = (i & 1) ? af1 : af0;
    bf16x8 afr[4];
#pragma unroll
    for (int tt = 0; tt < 4; ++tt)
#pragma unroll
      for (int j = 0; j < 8; ++j) afr[tt][j] = f2bf(afc[tt * 8 + j]);

    const char* bufc = (const char*)ldsb[cur];
    f32x4 acc[7][2] = {};
#pragma unroll
    for (int dj = 0; dj < 7; ++dj) {
      int rl = w + dj;
      int b0 = (rl * NPOS + lp) << 8;
      int b1 = (rl * NPOS + p1) << 8;
#pragma unroll
      for (int tt = 0; tt < 4; ++tt) {
        bf16x8 v0 = *(const bf16x8*)(bufc + (b0 + cosw0[tt]));
        bf16x8 v1 = *(const bf16x8*)(bufc + (b1 + cosw1[tt]));
        acc[dj][0] = __builtin_amdgcn_mfma_f32_16x16x32_bf16(afr[tt], v0,
                                                             acc[dj][0], 0, 0, 0);
        acc[dj][1] = __builtin_amdgcn_mfma_f32_16x16x32_bf16(afr[tt], v1,
                                                             acc[dj][1], 0, 0, 0);
      }
    }

    // ---- epilogue: LDS transpose in consumed buffer -> dense stores --------
    __syncthreads();  // all reads of buf[cur] done; reuse as scratch
    float* sc = (float*)ldsb[cur];  // [49][8][16] f32, col-swizzled by +k
#pragma unroll
    for (int dj = 0; dj < 7; ++dj) {
#pragma unroll
      for (int nt = 0; nt < 2; ++nt) {
        int post = lp + 16 * nt;
#pragma unroll
        for (int r = 0; r < 4; ++r) {
          int xlc = 4 * lg + r;
          int di = post - xlc;
          if (di >= 0 && di <= 6) {
            int k = dj * 7 + di;
            sc[k * 128 + w * 16 + ((xlc + k) & 15)] = acc[dj][nt][r];
          }
        }
      }
    }
    __syncthreads();

    float* ob = out + (size_t)(b * KK) * HWSZ + (size_t)ybase * WW + X0;
#pragma unroll
    for (int ii = 0; ii < 13; ++ii) {
      int e = tid + ii * 512;
      if (e < KK * 128) {
        int k = e >> 7;
        int yr = (e >> 4) & 7;
        int px = e & 15;
        float v = sc[k * 128 + yr * 16 + ((px + k) & 15)] * (1.0f / 128.0f);
        v = (v > 0.0f) ? v : 0.1f * v;
        ob[(size_t)k * HWSZ + yr * WW + px] = v;
      }
    }
  }
}

// ---------------- launch ----------------------------------------------------
extern "C" void kernel_launch(void* const* d_in, const int* in_sizes, int n_in,
                              void* d_out, int out_size, void* d_ws,
                              size_t ws_size, hipStream_t stream) {
  const float* tenOne = (const float*)d_in[0];
  const float* tenTwo = (const float*)d_in[1];
  const float* tenFlow = (const float*)d_in[2];

  __hip_bfloat16* wt = (__hip_bfloat16*)d_ws;
  border_kernel<<<256, 256, 0, stream>>>(wt);

  if (ws_size >= WS_NEED) {
    __hip_bfloat16* two_t = (__hip_bfloat16*)((char*)d_ws + WT_BYTES);
    transpose_kernel<<<BB * (HWSZ / 32), 256, 0, stream>>>(tenTwo, two_t);
    warp_fast<<<512, 1024, 0, stream>>>(two_t, tenFlow, wt);
  } else {
    int blocks = (BB * HWSZ + 255) / 256;
    warp_fallback<<<blocks, 256, 0, stream>>>(tenTwo, tenFlow, wt);
  }
  corr_kernel<<<256, 512, 0, stream>>>(tenOne, wt, (float*)d_out);
}

// Round 13
// 181.197 us; speedup vs baseline: 1.3472x; 1.3472x over previous
//
#include <hip/hip_runtime.h>
#include <hip/hip_bf16.h>

// Shapes fixed by setup_inputs(): B=2, C=128, H=256, W=448, stride=1.
#define BB 2
#define CC 128
#define HH 256
#define WW 448
#define KK 49
#define HWSZ (HH * WW)
#define PW 456  // padded width of wt: px = x+4, x in [-4, 452)

#define WT_BYTES ((size_t)BB * HH * PW * CC * 2)      // 59,768,832
#define TWT_BYTES ((size_t)BB * HH * WW * CC * 2)     // 58,720,256
#define WS_NEED (WT_BYTES + TWT_BYTES)

typedef __attribute__((ext_vector_type(8))) short bf16x8;
typedef __attribute__((ext_vector_type(4))) float f32x4;
typedef __attribute__((ext_vector_type(8))) unsigned short u16x8;

static __device__ __forceinline__ short f2bf(float v) {
  __hip_bfloat16 h = __float2bfloat16(v);
  return *reinterpret_cast<short*>(&h);
}
static __device__ __forceinline__ float bf2f(unsigned short u) {
  unsigned int x = ((unsigned int)u) << 16;
  return __uint_as_float(x);
}

typedef const __attribute__((address_space(1))) unsigned int* as1_u32p;
typedef __attribute__((address_space(3))) unsigned int* as3_u32p;
static __device__ __forceinline__ void gload_lds16(const void* g, void* l) {
  __builtin_amdgcn_global_load_lds((as1_u32p)g, (as3_u32p)l, 16, 0, 0);
}

#define VMW(N)                                          \
  asm volatile("s_waitcnt vmcnt(" #N ")" ::: "memory"); \
  __builtin_amdgcn_sched_barrier(0)
#define LGW0                                          \
  asm volatile("s_waitcnt lgkmcnt(0)" ::: "memory"); \
  __builtin_amdgcn_sched_barrier(0)

// ---------------- Kernel 0: zero the x-padding borders of wt ----------------
// Also guarantees wt bytes [0,1024) are zero (row 0, px 0..3) -> used as the
// zero-source for OOB staging loads in corr.
__global__ __launch_bounds__(256) void border_kernel(__hip_bfloat16* wt) {
  int i = blockIdx.x * 256 + threadIdx.x;  // 65536
  int by = i >> 7;
  int r = i & 127;
  int ps = r >> 4;
  int c16 = r & 15;
  int px = (ps < 4) ? ps : (448 + ps);
  u16x8 z = {0, 0, 0, 0, 0, 0, 0, 0};
  *(u16x8*)((char*)wt + ((size_t)((size_t)by * PW + px) * CC + c16 * 8) * 2) = z;
}

// ---------------- Kernel T: transpose tenTwo [c][p] f32 -> two_t [p][c] bf16
__global__ __launch_bounds__(256) void transpose_kernel(
    const float* __restrict__ two, __hip_bfloat16* __restrict__ two_t) {
  __shared__ float lds[128 * 33];
  int bid = blockIdx.x;            // BB * 3584
  int b = bid / (HWSZ / 32);
  int tile = bid - b * (HWSZ / 32);
  int P0 = tile * 32;

  const float* src = two + (size_t)b * CC * HWSZ + P0;
  int t = threadIdx.x;
  int bc = t >> 3;   // 0..31
  int f = t & 7;     // 0..7
#pragma unroll
  for (int k = 0; k < 4; ++k) {
    int c = bc + k * 32;
    float4 v = *(const float4*)(src + (size_t)c * HWSZ + f * 4);
    float* d = &lds[c * 33 + f * 4];
    d[0] = v.x; d[1] = v.y; d[2] = v.z; d[3] = v.w;
  }
  __syncthreads();

  int q = t & 7;     // c-chunk of 16
  int pl = t >> 3;   // 0..31 pixel
  int cs = q * 16;
  u16x8 pk0, pk1;
#pragma unroll
  for (int j = 0; j < 8; ++j)
    pk0[j] = (unsigned short)f2bf(lds[(cs + j) * 33 + pl]);
#pragma unroll
  for (int j = 0; j < 8; ++j)
    pk1[j] = (unsigned short)f2bf(lds[(cs + 8 + j) * 33 + pl]);
  char* dst = (char*)two_t + ((size_t)((size_t)b * HWSZ + P0 + pl) * CC + cs) * 2;
  *(u16x8*)dst = pk0;
  *(u16x8*)(dst + 16) = pk1;
}

// ---------------- Kernel 1 (fast): gather from two_t [p][c] bf16 -----------
__global__ __launch_bounds__(1024) void warp_fast(
    const __hip_bfloat16* __restrict__ two_t, const float* __restrict__ flow,
    __hip_bfloat16* __restrict__ wt) {
  int wg = (blockIdx.x & 7) * 64 + (blockIdx.x >> 3);  // bijective, 512
  int b = wg >> 8;
  int y = wg & 255;
  int pg = threadIdx.x >> 4;  // 0..63 pixel group
  int cw = threadIdx.x & 15;  // 16B channel chunk

  const char* tb = (const char*)two_t + (size_t)b * HWSZ * (CC * 2);
  char* wb = (char*)wt + ((size_t)(b * HH + y) * PW + 4) * (CC * 2);
  const float* fxp = flow + (size_t)(b * 2 + 0) * HWSZ + y * WW;
  const float* fyp = flow + (size_t)(b * 2 + 1) * HWSZ + y * WW;

#pragma unroll 2
  for (int it = 0; it < 7; ++it) {
    int x = it * 64 + pg;

    float fx = fxp[x] * 2.5f;
    float fy = fyp[x] * 2.5f;
    float px = (float)x + fx;
    float py = (float)y + fy;
    float x0f = floorf(px), y0f = floorf(py);
    int x0 = (int)x0f, y0 = (int)y0f;
    int x1 = x0 + 1, y1 = y0 + 1;
    float wx1 = px - x0f, wx0 = 1.0f - wx1;
    float wy1 = py - y0f, wy0 = 1.0f - wy1;
    bool vx0 = (x0 >= 0) && (x0 < WW);
    bool vx1 = (x1 >= 0) && (x1 < WW);
    bool vy0 = (y0 >= 0) && (y0 < HH);
    bool vy1 = (y1 >= 0) && (y1 < HH);
    float w00 = (vx0 && vy0) ? wx0 * wy0 : 0.0f;
    float w01 = (vx1 && vy0) ? wx1 * wy0 : 0.0f;
    float w10 = (vx0 && vy1) ? wx0 * wy1 : 0.0f;
    float w11 = (vx1 && vy1) ? wx1 * wy1 : 0.0f;
    int cx0 = min(max(x0, 0), WW - 1);
    int cx1 = min(max(x1, 0), WW - 1);
    int cy0 = min(max(y0, 0), HH - 1);
    int cy1 = min(max(y1, 0), HH - 1);

    u16x8 a = *(const u16x8*)(tb + ((size_t)cy0 * WW + cx0) * 256 + cw * 16);
    u16x8 bb_ = *(const u16x8*)(tb + ((size_t)cy0 * WW + cx1) * 256 + cw * 16);
    u16x8 c = *(const u16x8*)(tb + ((size_t)cy1 * WW + cx0) * 256 + cw * 16);
    u16x8 d = *(const u16x8*)(tb + ((size_t)cy1 * WW + cx1) * 256 + cw * 16);

    u16x8 pk;
#pragma unroll
    for (int e = 0; e < 8; ++e) {
      float v = w00 * bf2f((unsigned short)a[e]) +
                w01 * bf2f((unsigned short)bb_[e]) +
                w10 * bf2f((unsigned short)c[e]) +
                w11 * bf2f((unsigned short)d[e]);
      pk[e] = (unsigned short)f2bf(v);
    }
    *(u16x8*)(wb + (size_t)x * 256 + cw * 16) = pk;
  }
}

// ---------------- Kernel 1 (fallback): gather f32 planes directly -----------
__global__ __launch_bounds__(256) void warp_fallback(
    const float* __restrict__ two, const float* __restrict__ flow,
    __hip_bfloat16* __restrict__ wt) {
  int idx = blockIdx.x * 256 + threadIdx.x;
  if (idx >= BB * HWSZ) return;
  int x = idx % WW;
  int y = (idx / WW) % HH;
  int b = idx / HWSZ;

  float fx = flow[(b * 2 + 0) * HWSZ + y * WW + x] * 2.5f;
  float fy = flow[(b * 2 + 1) * HWSZ + y * WW + x] * 2.5f;
  float px = (float)x + fx;
  float py = (float)y + fy;
  float x0f = floorf(px), y0f = floorf(py);
  int x0 = (int)x0f, y0 = (int)y0f;
  int x1 = x0 + 1, y1 = y0 + 1;
  float wx1 = px - x0f, wx0 = 1.0f - wx1;
  float wy1 = py - y0f, wy0 = 1.0f - wy1;
  bool vx0 = (x0 >= 0) && (x0 < WW);
  bool vx1 = (x1 >= 0) && (x1 < WW);
  bool vy0 = (y0 >= 0) && (y0 < HH);
  bool vy1 = (y1 >= 0) && (y1 < HH);
  float w00 = (vx0 && vy0) ? wx0 * wy0 : 0.0f;
  float w01 = (vx1 && vy0) ? wx1 * wy0 : 0.0f;
  float w10 = (vx0 && vy1) ? wx0 * wy1 : 0.0f;
  float w11 = (vx1 && vy1) ? wx1 * wy1 : 0.0f;
  int cx0 = min(max(x0, 0), WW - 1);
  int cx1 = min(max(x1, 0), WW - 1);
  int cy0 = min(max(y0, 0), HH - 1);
  int cy1 = min(max(y1, 0), HH - 1);
  int o00 = cy0 * WW + cx0;
  int o01 = cy0 * WW + cx1;
  int o10 = cy1 * WW + cx0;
  int o11 = cy1 * WW + cx1;

  const float* p = two + (size_t)b * CC * HWSZ;
  char* wo = (char*)wt + ((size_t)((size_t)(b * HH + y) * PW) + x + 4) * CC * 2;
#pragma unroll 4
  for (int j = 0; j < 16; ++j) {
    u16x8 pk;
#pragma unroll
    for (int jj = 0; jj < 8; ++jj) {
      int c = j * 8 + jj;
      const float* pc = p + (size_t)c * HWSZ;
      float v = w00 * pc[o00] + w01 * pc[o01] + w10 * pc[o10] + w11 * pc[o11];
      pk[jj] = (unsigned short)f2bf(v);
    }
    *(u16x8*)(wo + j * 16) = pk;
  }
}

// ---------------- Kernel 2: persistent pipelined MFMA correlation -----------
// 256 blocks x 7 tiles, double-buffered 2x78.8KB LDS. Counted vmcnt keeps
// tile i+1's 42 loads in flight across tile i's barriers (raw s_barrier).
// Uniform issue counts: OOB rows read wt's zeroed border bytes [0,1024);
// tail waves stage into a dummy LDS slot.
#define YTB 8
#define NROWS 14               // YTB + 6
#define NPOS 22
#define ROWCH (NPOS * 16)      // 352 16B-chunks per row
#define CHUNKS (NROWS * ROWCH) // 4928 chunks = 78,848 B

__global__ __launch_bounds__(512) void corr_kernel(
    const float* __restrict__ one, const __hip_bfloat16* __restrict__ wt,
    float* __restrict__ out) {
  __shared__ uint4 ldsb[2][CHUNKS];  // 157,696 B
  __shared__ uint4 dummy[64];        // tail-wave staging sink (1 KB)

  int bid = blockIdx.x;  // 0..255
  int sbid = (bid & 7) * 32 + (bid >> 3);  // XCD-chunked tile order, bijective
  int tid = threadIdx.x;
  int w = tid >> 6;
  int l = tid & 63;
  int lp = l & 15;
  int lg = l >> 4;

  // tile-invariant staging descriptors
  int srow[10], soff[10];
#pragma unroll
  for (int k = 0; k < 10; ++k) {
    int ci = tid + k * 512;
    int row = ci / ROWCH;
    int r2 = ci - row * ROWCH;
    int p = r2 >> 4;
    int cw = r2 & 15;
    int cwS = cw ^ (p & 7);  // pre-swizzled SOURCE, linear DEST
    srow[k] = row;
    soff[k] = row * (PW * CC * 2) + p * 256 + cwS * 16;
  }
  int p1 = (lp + 16 < 21) ? (lp + 16) : 21;
  int cosw0[4], cosw1[4];
#pragma unroll
  for (int t = 0; t < 4; ++t) {
    int co = t * 64 + lg * 16;
    cosw0[t] = co ^ ((lp & 7) << 4);
    cosw1[t] = co ^ ((p1 & 7) << 4);
  }
  const char* zpad = (const char*)wt + l * 16;  // bytes [0,1024) are zero
  bool tailwave = (w >= 5);                     // k=9 invalid for waves 5..7

#define TDECODE(T, B_, XT_, YT_)      \
  int B_ = (T) / 896;                 \
  int rem_##B_ = (T)-B_ * 896;        \
  int XT_ = rem_##B_ >> 5;            \
  int YT_ = rem_##B_ & 31;

#define STAGE(T, SEL)                                                         \
  {                                                                           \
    TDECODE(T, sb, sxt, syt)                                                  \
    int sybase = syt * YTB;                                                   \
    const char* gb = (const char*)wt +                                        \
                     (((size_t)(sb * HH) + sybase - 3) * PW + sxt * 16 + 1) * \
                         (CC * 2);                                            \
    _Pragma("unroll") for (int k = 0; k < 10; ++k) {                          \
      int yy = sybase - 3 + srow[k];                                          \
      bool inv = (k == 9) && tailwave;                                        \
      bool oob = (yy < 0) || (yy >= HH);                                      \
      const char* src = (oob || inv) ? zpad : (gb + soff[k]);                 \
      char* dst = inv ? (char*)dummy                                          \
                      : ((char*)ldsb + (SEL) * (CHUNKS * 16) +                \
                         (size_t)(k * 512 + (tid & ~63)) * 16);               \
      gload_lds16(src, dst);                                                  \
    }                                                                         \
  }

#define ALOAD(T, AF)                                                     \
  {                                                                      \
    TDECODE(T, ab, axt, ayt)                                             \
    const float* Ab = one + ((size_t)(ab * CC) * HH + ayt * YTB + w) *   \
                                WW + axt * 16 + lp;                      \
    _Pragma("unroll") for (int tt = 0; tt < 4; ++tt)                     \
        _Pragma("unroll") for (int j = 0; j < 8; ++j)                    \
            AF[tt * 8 + j] = Ab[(size_t)(tt * 32 + lg * 8 + j) * HWSZ];  \
  }

#define CVT(AF)                                        \
  _Pragma("unroll") for (int tt = 0; tt < 4; ++tt)     \
      _Pragma("unroll") for (int j = 0; j < 8; ++j)    \
          afr[tt][j] = f2bf(AF[tt * 8 + j]);

  float afA[32], afB[32];

  // prologue: tile 0
  STAGE(sbid, 0)
  ALOAD(sbid, afA)

  int cur = 0;
#pragma unroll 1
  for (int i = 0; i < 7; ++i) {
    int t = i * 256 + sbid;
    TDECODE(t, b, xt, yt)
    int ybase = yt * YTB;
    int X0 = xt * 16;

    if (i < 6) {
      int tn = (i + 1) * 256 + sbid;
      STAGE(tn, cur ^ 1)
      if (i & 1) { ALOAD(tn, afA) } else { ALOAD(tn, afB) }
      __builtin_amdgcn_sched_barrier(0);
      VMW(42);  // tile i's 42 loads (older than the 42 just issued) complete
    } else {
      VMW(12);  // only epi(i-1) stores may remain newer than tile-6 loads
    }
    LGW0;
    __builtin_amdgcn_s_barrier();  // B1: buf[cur] fully staged
    __builtin_amdgcn_sched_barrier(0);

    // ---- compute tile i ---------------------------------------------------
    bf16x8 afr[4];
    if (i & 1) { CVT(afB) } else { CVT(afA) }

    const char* bufc = (const char*)ldsb + cur * (CHUNKS * 16);
    f32x4 acc[7][2] = {};
#pragma unroll
    for (int dj = 0; dj < 7; ++dj) {
      int rl = w + dj;
      int b0 = (rl * NPOS + lp) << 8;
      int b1 = (rl * NPOS + p1) << 8;
#pragma unroll
      for (int tt = 0; tt < 4; ++tt) {
        bf16x8 v0 = *(const bf16x8*)(bufc + (b0 + cosw0[tt]));
        bf16x8 v1 = *(const bf16x8*)(bufc + (b1 + cosw1[tt]));
        acc[dj][0] = __builtin_amdgcn_mfma_f32_16x16x32_bf16(afr[tt], v0,
                                                             acc[dj][0], 0, 0, 0);
        acc[dj][1] = __builtin_amdgcn_mfma_f32_16x16x32_bf16(afr[tt], v1,
                                                             acc[dj][1], 0, 0, 0);
      }
    }

    LGW0;
    __builtin_amdgcn_s_barrier();  // B2: all reads of buf[cur] done
    __builtin_amdgcn_sched_barrier(0);

    // ---- epilogue: transpose in consumed buffer -> dense stores -----------
    float* sc = (float*)((char*)ldsb + cur * (CHUNKS * 16));
#pragma unroll
    for (int dj = 0; dj < 7; ++dj) {
#pragma unroll
      for (int nt = 0; nt < 2; ++nt) {
        int post = lp + 16 * nt;
#pragma unroll
        for (int r = 0; r < 4; ++r) {
          int xlc = 4 * lg + r;
          int di = post - xlc;
          if (di >= 0 && di <= 6) {
            int k = dj * 7 + di;
            sc[k * 128 + w * 16 + ((xlc + k) & 15)] = acc[dj][nt][r];
          }
        }
      }
    }
    LGW0;
    __builtin_amdgcn_s_barrier();  // B3: sc written
    __builtin_amdgcn_sched_barrier(0);

    float* ob = out + (size_t)(b * KK) * HWSZ + (size_t)ybase * WW + X0;
#pragma unroll
    for (int ii = 0; ii < 13; ++ii) {
      int e = tid + ii * 512;
      if (e < KK * 128) {
        int k = e >> 7;
        int yr = (e >> 4) & 7;
        int px = e & 15;
        float v = sc[k * 128 + yr * 16 + ((px + k) & 15)] * (1.0f / 128.0f);
        v = (v > 0.0f) ? v : 0.1f * v;
        ob[(size_t)k * HWSZ + yr * WW + px] = v;
      }
    }
    LGW0;
    __builtin_amdgcn_s_barrier();  // B4: sc (=buf[cur]) free as stage target
    __builtin_amdgcn_sched_barrier(0);
    cur ^= 1;
  }
}

// ---------------- launch ----------------------------------------------------
extern "C" void kernel_launch(void* const* d_in, const int* in_sizes, int n_in,
                              void* d_out, int out_size, void* d_ws,
                              size_t ws_size, hipStream_t stream) {
  const float* tenOne = (const float*)d_in[0];
  const float* tenTwo = (const float*)d_in[1];
  const float* tenFlow = (const float*)d_in[2];

  __hip_bfloat16* wt = (__hip_bfloat16*)d_ws;
  border_kernel<<<256, 256, 0, stream>>>(wt);

  if (ws_size >= WS_NEED) {
    __hip_bfloat16* two_t = (__hip_bfloat16*)((char*)d_ws + WT_BYTES);
    transpose_kernel<<<BB * (HWSZ / 32), 256, 0, stream>>>(tenTwo, two_t);
    warp_fast<<<512, 1024, 0, stream>>>(two_t, tenFlow, wt);
  } else {
    int blocks = (BB * HWSZ + 255) / 256;
    warp_fallback<<<blocks, 256, 0, stream>>>(tenTwo, tenFlow, wt);
  }
  corr_kernel<<<256, 512, 0, stream>>>(tenOne, wt, (float*)d_out);
}

// Round 14
// 136.406 us; speedup vs baseline: 1.7896x; 1.3284x over previous
//
#include <hip/hip_runtime.h>
#include <hip/hip_bf16.h>

// Shapes fixed by setup_inputs(): B=2, C=128, H=256, W=448, stride=1.
#define BB 2
#define CC 128
#define HH 256
#define WW 448
#define KK 49
#define HWSZ (HH * WW)
#define PW 456  // padded width of wt: px = x+4, x in [-4, 452)

#define WT_BYTES ((size_t)BB * HH * PW * CC * 2)      // 59,768,832
#define TWT_BYTES ((size_t)BB * HH * WW * CC * 2)     // 58,720,256
#define WS_NEED (WT_BYTES + TWT_BYTES)

typedef __attribute__((ext_vector_type(8))) short bf16x8;
typedef __attribute__((ext_vector_type(4))) float f32x4;
typedef __attribute__((ext_vector_type(8))) unsigned short u16x8;

static __device__ __forceinline__ short f2bf(float v) {
  __hip_bfloat16 h = __float2bfloat16(v);
  return *reinterpret_cast<short*>(&h);
}
static __device__ __forceinline__ float bf2f(unsigned short u) {
  unsigned int x = ((unsigned int)u) << 16;
  return __uint_as_float(x);
}

typedef const __attribute__((address_space(1))) unsigned int* as1_u32p;
typedef __attribute__((address_space(3))) unsigned int* as3_u32p;
static __device__ __forceinline__ void gload_lds16(const void* g, void* l) {
  __builtin_amdgcn_global_load_lds((as1_u32p)g, (as3_u32p)l, 16, 0, 0);
}

// ---------------- Kernel 0: zero the x-padding borders of wt ----------------
__global__ __launch_bounds__(256) void border_kernel(__hip_bfloat16* wt) {
  int i = blockIdx.x * 256 + threadIdx.x;  // 65536
  int by = i >> 7;
  int r = i & 127;
  int ps = r >> 4;
  int c16 = r & 15;
  int px = (ps < 4) ? ps : (448 + ps);
  u16x8 z = {0, 0, 0, 0, 0, 0, 0, 0};
  *(u16x8*)((char*)wt + ((size_t)((size_t)by * PW + px) * CC + c16 * 8) * 2) = z;
}

// ---------------- Kernel T: transpose tenTwo [c][p] f32 -> two_t [p][c] bf16
__global__ __launch_bounds__(256) void transpose_kernel(
    const float* __restrict__ two, __hip_bfloat16* __restrict__ two_t) {
  __shared__ float lds[128 * 33];
  int bid = blockIdx.x;            // BB * 3584
  int b = bid / (HWSZ / 32);
  int tile = bid - b * (HWSZ / 32);
  int P0 = tile * 32;

  const float* src = two + (size_t)b * CC * HWSZ + P0;
  int t = threadIdx.x;
  int bc = t >> 3;   // 0..31
  int f = t & 7;     // 0..7
#pragma unroll
  for (int k = 0; k < 4; ++k) {
    int c = bc + k * 32;
    float4 v = *(const float4*)(src + (size_t)c * HWSZ + f * 4);
    float* d = &lds[c * 33 + f * 4];
    d[0] = v.x; d[1] = v.y; d[2] = v.z; d[3] = v.w;
  }
  __syncthreads();

  int q = t & 7;     // c-chunk of 16
  int pl = t >> 3;   // 0..31 pixel
  int cs = q * 16;
  u16x8 pk0, pk1;
#pragma unroll
  for (int j = 0; j < 8; ++j)
    pk0[j] = (unsigned short)f2bf(lds[(cs + j) * 33 + pl]);
#pragma unroll
  for (int j = 0; j < 8; ++j)
    pk1[j] = (unsigned short)f2bf(lds[(cs + 8 + j) * 33 + pl]);
  char* dst = (char*)two_t + ((size_t)((size_t)b * HWSZ + P0 + pl) * CC + cs) * 2;
  *(u16x8*)dst = pk0;
  *(u16x8*)(dst + 16) = pk1;
}

// ---------------- Kernel 1 (fast): gather from two_t [p][c] bf16 -----------
__global__ __launch_bounds__(1024) void warp_fast(
    const __hip_bfloat16* __restrict__ two_t, const float* __restrict__ flow,
    __hip_bfloat16* __restrict__ wt) {
  int wg = (blockIdx.x & 7) * 64 + (blockIdx.x >> 3);  // bijective, 512
  int b = wg >> 8;
  int y = wg & 255;
  int pg = threadIdx.x >> 4;  // 0..63 pixel group
  int cw = threadIdx.x & 15;  // 16B channel chunk

  const char* tb = (const char*)two_t + (size_t)b * HWSZ * (CC * 2);
  char* wb = (char*)wt + ((size_t)(b * HH + y) * PW + 4) * (CC * 2);
  const float* fxp = flow + (size_t)(b * 2 + 0) * HWSZ + y * WW;
  const float* fyp = flow + (size_t)(b * 2 + 1) * HWSZ + y * WW;

#pragma unroll 2
  for (int it = 0; it < 7; ++it) {
    int x = it * 64 + pg;

    float fx = fxp[x] * 2.5f;
    float fy = fyp[x] * 2.5f;
    float px = (float)x + fx;
    float py = (float)y + fy;
    float x0f = floorf(px), y0f = floorf(py);
    int x0 = (int)x0f, y0 = (int)y0f;
    int x1 = x0 + 1, y1 = y0 + 1;
    float wx1 = px - x0f, wx0 = 1.0f - wx1;
    float wy1 = py - y0f, wy0 = 1.0f - wy1;
    bool vx0 = (x0 >= 0) && (x0 < WW);
    bool vx1 = (x1 >= 0) && (x1 < WW);
    bool vy0 = (y0 >= 0) && (y0 < HH);
    bool vy1 = (y1 >= 0) && (y1 < HH);
    float w00 = (vx0 && vy0) ? wx0 * wy0 : 0.0f;
    float w01 = (vx1 && vy0) ? wx1 * wy0 : 0.0f;
    float w10 = (vx0 && vy1) ? wx0 * wy1 : 0.0f;
    float w11 = (vx1 && vy1) ? wx1 * wy1 : 0.0f;
    int cx0 = min(max(x0, 0), WW - 1);
    int cx1 = min(max(x1, 0), WW - 1);
    int cy0 = min(max(y0, 0), HH - 1);
    int cy1 = min(max(y1, 0), HH - 1);

    u16x8 a = *(const u16x8*)(tb + ((size_t)cy0 * WW + cx0) * 256 + cw * 16);
    u16x8 bb_ = *(const u16x8*)(tb + ((size_t)cy0 * WW + cx1) * 256 + cw * 16);
    u16x8 c = *(const u16x8*)(tb + ((size_t)cy1 * WW + cx0) * 256 + cw * 16);
    u16x8 d = *(const u16x8*)(tb + ((size_t)cy1 * WW + cx1) * 256 + cw * 16);

    u16x8 pk;
#pragma unroll
    for (int e = 0; e < 8; ++e) {
      float v = w00 * bf2f((unsigned short)a[e]) +
                w01 * bf2f((unsigned short)bb_[e]) +
                w10 * bf2f((unsigned short)c[e]) +
                w11 * bf2f((unsigned short)d[e]);
      pk[e] = (unsigned short)f2bf(v);
    }
    *(u16x8*)(wb + (size_t)x * 256 + cw * 16) = pk;
  }
}

// ---------------- Kernel 1 (fallback): gather f32 planes directly -----------
__global__ __launch_bounds__(256) void warp_fallback(
    const float* __restrict__ two, const float* __restrict__ flow,
    __hip_bfloat16* __restrict__ wt) {
  int idx = blockIdx.x * 256 + threadIdx.x;
  if (idx >= BB * HWSZ) return;
  int x = idx % WW;
  int y = (idx / WW) % HH;
  int b = idx / HWSZ;

  float fx = flow[(b * 2 + 0) * HWSZ + y * WW + x] * 2.5f;
  float fy = flow[(b * 2 + 1) * HWSZ + y * WW + x] * 2.5f;
  float px = (float)x + fx;
  float py = (float)y + fy;
  float x0f = floorf(px), y0f = floorf(py);
  int x0 = (int)x0f, y0 = (int)y0f;
  int x1 = x0 + 1, y1 = y0 + 1;
  float wx1 = px - x0f, wx0 = 1.0f - wx1;
  float wy1 = py - y0f, wy0 = 1.0f - wy1;
  bool vx0 = (x0 >= 0) && (x0 < WW);
  bool vx1 = (x1 >= 0) && (x1 < WW);
  bool vy0 = (y0 >= 0) && (y0 < HH);
  bool vy1 = (y1 >= 0) && (y1 < HH);
  float w00 = (vx0 && vy0) ? wx0 * wy0 : 0.0f;
  float w01 = (vx1 && vy0) ? wx1 * wy0 : 0.0f;
  float w10 = (vx0 && vy1) ? wx0 * wy1 : 0.0f;
  float w11 = (vx1 && vy1) ? wx1 * wy1 : 0.0f;
  int cx0 = min(max(x0, 0), WW - 1);
  int cx1 = min(max(x1, 0), WW - 1);
  int cy0 = min(max(y0, 0), HH - 1);
  int cy1 = min(max(y1, 0), HH - 1);
  int o00 = cy0 * WW + cx0;
  int o01 = cy0 * WW + cx1;
  int o10 = cy1 * WW + cx0;
  int o11 = cy1 * WW + cx1;

  const float* p = two + (size_t)b * CC * HWSZ;
  char* wo = (char*)wt + ((size_t)((size_t)(b * HH + y) * PW) + x + 4) * CC * 2;
#pragma unroll 4
  for (int j = 0; j < 16; ++j) {
    u16x8 pk;
#pragma unroll
    for (int jj = 0; jj < 8; ++jj) {
      int c = j * 8 + jj;
      const float* pc = p + (size_t)c * HWSZ;
      float v = w00 * pc[o00] + w01 * pc[o01] + w10 * pc[o10] + w11 * pc[o11];
      pk[jj] = (unsigned short)f2bf(v);
    }
    *(u16x8*)(wo + j * 16) = pk;
  }
}

// ---------------- Kernel 2: correlation via MFMA (R11 structure) ------------
// Swizzle upgraded 3-bit -> 4-bit: stage source cw^(p&15), read co^(pos<<4).
// Chunk%32 per wave = 16(lp&1) + (4t+lg)^lp -> 2 lanes/bank-quad (free),
// was 4-way with (p&7).
#define YTB 8
#define NROWS 14               // YTB + 6
#define NPOS 22
#define ROWCH (NPOS * 16)      // 352 16B-chunks per row
#define CHUNKS (NROWS * ROWCH) // 4928 chunks = 78,848 B

__global__ __launch_bounds__(512, 4) void corr_kernel(
    const float* __restrict__ one, const __hip_bfloat16* __restrict__ wt,
    float* __restrict__ out) {
  __shared__ uint4 ldsb[CHUNKS];

  int bid = blockIdx.x;                    // 1792 = 8 * 224
  int wg = (bid & 7) * 224 + (bid >> 3);   // XCD-chunked, bijective
  int b = wg / 896;
  int rem = wg - b * 896;
  int xt = rem >> 5;   // 0..27
  int yt = rem & 31;   // 0..31
  int ybase = yt * YTB;
  int X0 = xt * 16;
  int tid = threadIdx.x;
  int w = tid >> 6;   // wave 0..7
  int l = tid & 63;
  int lp = l & 15;
  int lg = l >> 4;
  int y = ybase + w;

  const char* wbase =
      (const char*)wt + (((size_t)(b * HH)) * PW + X0 + 1) * (CC * 2);
  bool interior = (ybase >= 3) && (ybase + NROWS - 3 <= HH);  // rows all valid

  if (interior) {
    // ---- async staging straight to LDS; no VGPR round-trip ----------------
#pragma unroll
    for (int k = 0; k < 10; ++k) {
      int ci = tid + k * 512;
      // k=9 tail: 4928-4608=320 = 5 full waves -> wave-uniform predicate.
      if (k < 9 || tid < (CHUNKS - 9 * 512)) {
        int row = ci / ROWCH;
        int r2 = ci - row * ROWCH;
        int p = r2 >> 4;
        int cw = r2 & 15;
        int cwS = cw ^ (p & 15);  // pre-swizzled SOURCE (4-bit), linear DEST
        int yy = ybase - 3 + row;
        const char* g = wbase + (size_t)yy * (PW * CC * 2) + p * 256 + cwS * 16;
        int wave_ci0 = k * 512 + (tid & ~63);  // wave-uniform LDS base chunk
        gload_lds16(g, (char*)ldsb + (size_t)wave_ci0 * 16);
      }
    }
  } else {
    // ---- edge tiles: reg staging with zero fill (same LDS placement) ------
#pragma unroll
    for (int k = 0; k < 10; ++k) {
      int ci = tid + k * 512;
      if (ci < CHUNKS) {
        int row = ci / ROWCH;
        int r2 = ci - row * ROWCH;
        int p = r2 >> 4;
        int cw = r2 & 15;
        int yy = ybase - 3 + row;
        uint4 v = {0, 0, 0, 0};
        if (yy >= 0 && yy < HH)
          v = *(const uint4*)(wbase + (size_t)yy * (PW * CC * 2) + p * 256 +
                              cw * 16);
        *(uint4*)((char*)ldsb + ((ci * 16) ^ ((p & 15) << 4))) = v;
      }
    }
  }

  // ---- A fragments (independent of staging; overlaps in flight) -----------
  const float* Abase = one + ((size_t)(b * CC) * HH + y) * WW + X0 + lp;
  bf16x8 afr[4];
#pragma unroll
  for (int t = 0; t < 4; ++t)
#pragma unroll
    for (int j = 0; j < 8; ++j)
      afr[t][j] = f2bf(Abase[(size_t)(t * 32 + lg * 8 + j) * HWSZ]);

  __syncthreads();  // drains vmcnt (gload_lds) / lgkmcnt (edge ds_write)

  // ---- compute: pure ds_read_b128 + MFMA ----------------------------------
  int p1 = (lp + 16 < 21) ? (lp + 16) : 21;
  int cosw0[4], cosw1[4];
#pragma unroll
  for (int t = 0; t < 4; ++t) {
    int co = t * 64 + lg * 16;
    cosw0[t] = co ^ ((lp & 15) << 4);
    cosw1[t] = co ^ ((p1 & 15) << 4);
  }

  f32x4 acc[7][2] = {};
#pragma unroll
  for (int dj = 0; dj < 7; ++dj) {
    int rl = w + dj;  // LDS row for yy = y + dj - 3
    int b0 = (rl * NPOS + lp) << 8;
    int b1 = (rl * NPOS + p1) << 8;
#pragma unroll
    for (int t = 0; t < 4; ++t) {
      bf16x8 v0 = *(const bf16x8*)((const char*)ldsb + (b0 + cosw0[t]));
      bf16x8 v1 = *(const bf16x8*)((const char*)ldsb + (b1 + cosw1[t]));
      acc[dj][0] = __builtin_amdgcn_mfma_f32_16x16x32_bf16(afr[t], v0,
                                                           acc[dj][0], 0, 0, 0);
      acc[dj][1] = __builtin_amdgcn_mfma_f32_16x16x32_bf16(afr[t], v1,
                                                           acc[dj][1], 0, 0, 0);
    }
  }

  // ---- Epilogue: LDS transpose -> dense stores ----------------------------
  // D layout: col = lane&15 (+16*nt) = pos, row = 4*(lane>>4)+reg = x_local.
  __syncthreads();  // all ds_reads of ldsb done; safe to reuse as scratch
  float* sc = (float*)ldsb;  // [49][8][16] f32, col-swizzled by +k (mod 16)
#pragma unroll
  for (int dj = 0; dj < 7; ++dj) {
#pragma unroll
    for (int nt = 0; nt < 2; ++nt) {
      int post = lp + 16 * nt;
#pragma unroll
      for (int r = 0; r < 4; ++r) {
        int xlc = 4 * lg + r;
        int di = post - xlc;
        if (di >= 0 && di <= 6) {
          int k = dj * 7 + di;
          sc[k * 128 + w * 16 + ((xlc + k) & 15)] = acc[dj][nt][r];
        }
      }
    }
  }
  __syncthreads();

  float* ob = out + (size_t)(b * KK) * HWSZ + (size_t)ybase * WW + X0;
#pragma unroll
  for (int i = 0; i < 13; ++i) {
    int e = tid + i * 512;
    if (e < KK * 128) {
      int k = e >> 7;
      int yr = (e >> 4) & 7;
      int px = e & 15;
      float v = sc[k * 128 + yr * 16 + ((px + k) & 15)] * (1.0f / 128.0f);
      v = (v > 0.0f) ? v : 0.1f * v;
      ob[(size_t)k * HWSZ + yr * WW + px] = v;
    }
  }
}

// ---------------- launch ----------------------------------------------------
extern "C" void kernel_launch(void* const* d_in, const int* in_sizes, int n_in,
                              void* d_out, int out_size, void* d_ws,
                              size_t ws_size, hipStream_t stream) {
  const float* tenOne = (const float*)d_in[0];
  const float* tenTwo = (const float*)d_in[1];
  const float* tenFlow = (const float*)d_in[2];

  __hip_bfloat16* wt = (__hip_bfloat16*)d_ws;
  border_kernel<<<256, 256, 0, stream>>>(wt);

  if (ws_size >= WS_NEED) {
    __hip_bfloat16* two_t = (__hip_bfloat16*)((char*)d_ws + WT_BYTES);
    transpose_kernel<<<BB * (HWSZ / 32), 256, 0, stream>>>(tenTwo, two_t);
    warp_fast<<<512, 1024, 0, stream>>>(two_t, tenFlow, wt);
  } else {
    int blocks = (BB * HWSZ + 255) / 256;
    warp_fallback<<<blocks, 256, 0, stream>>>(tenTwo, tenFlow, wt);
  }
  corr_kernel<<<1792, 512, 0, stream>>>(tenOne, wt, (float*)d_out);
}

// Round 15
// 130.140 us; speedup vs baseline: 1.8757x; 1.0482x over previous
//
#include <hip/hip_runtime.h>
#include <hip/hip_bf16.h>

// Shapes fixed by setup_inputs(): B=2, C=128, H=256, W=448, stride=1.
#define BB 2
#define CC 128
#define HH 256
#define WW 448
#define KK 49
#define HWSZ (HH * WW)
#define PW 456  // padded width of wt: px = x+4, x in [-4, 452)

#define WT_BYTES ((size_t)BB * HH * PW * CC * 2)      // 59,768,832
#define TWT_BYTES ((size_t)BB * HH * WW * CC * 2)     // 58,720,256
#define WS_NEED (WT_BYTES + TWT_BYTES)

typedef __attribute__((ext_vector_type(8))) short bf16x8;
typedef __attribute__((ext_vector_type(4))) float f32x4;
typedef __attribute__((ext_vector_type(8))) unsigned short u16x8;

static __device__ __forceinline__ short f2bf(float v) {
  __hip_bfloat16 h = __float2bfloat16(v);
  return *reinterpret_cast<short*>(&h);
}
static __device__ __forceinline__ float bf2f(unsigned short u) {
  unsigned int x = ((unsigned int)u) << 16;
  return __uint_as_float(x);
}

typedef const __attribute__((address_space(1))) unsigned int* as1_u32p;
typedef __attribute__((address_space(3))) unsigned int* as3_u32p;
static __device__ __forceinline__ void gload_lds16(const void* g, void* l) {
  __builtin_amdgcn_global_load_lds((as1_u32p)g, (as3_u32p)l, 16, 0, 0);
}

// ---------------- Kernel 0 (fallback path only): zero wt x-pad borders ------
__global__ __launch_bounds__(256) void border_kernel(__hip_bfloat16* wt) {
  int i = blockIdx.x * 256 + threadIdx.x;  // 65536
  int by = i >> 7;
  int r = i & 127;
  int ps = r >> 4;
  int c16 = r & 15;
  int px = (ps < 4) ? ps : (448 + ps);
  u16x8 z = {0, 0, 0, 0, 0, 0, 0, 0};
  *(u16x8*)((char*)wt + ((size_t)((size_t)by * PW + px) * CC + c16 * 8) * 2) = z;
}

// ---------------- Kernel T: transpose tenTwo [c][p] f32 -> two_t [p][c] bf16
// Blocks 0..255 additionally zero wt's x-pad borders (disjoint buffer; the
// consumer corr_kernel launches later in-stream).
__global__ __launch_bounds__(256) void transpose_kernel(
    const float* __restrict__ two, __hip_bfloat16* __restrict__ two_t,
    __hip_bfloat16* __restrict__ wt) {
  __shared__ float lds[128 * 33];
  int bid = blockIdx.x;            // BB * 3584 = 7168
  if (bid < 256) {                 // folded border zeroing (1 MB total)
    int i = bid * 256 + threadIdx.x;
    int by = i >> 7;
    int r = i & 127;
    int ps = r >> 4;
    int c16 = r & 15;
    int px = (ps < 4) ? ps : (448 + ps);
    u16x8 z = {0, 0, 0, 0, 0, 0, 0, 0};
    *(u16x8*)((char*)wt + ((size_t)((size_t)by * PW + px) * CC + c16 * 8) * 2) =
        z;
  }
  int b = bid / (HWSZ / 32);
  int tile = bid - b * (HWSZ / 32);
  int P0 = tile * 32;

  const float* src = two + (size_t)b * CC * HWSZ + P0;
  int t = threadIdx.x;
  int bc = t >> 3;   // 0..31
  int f = t & 7;     // 0..7
#pragma unroll
  for (int k = 0; k < 4; ++k) {
    int c = bc + k * 32;
    float4 v = *(const float4*)(src + (size_t)c * HWSZ + f * 4);
    float* d = &lds[c * 33 + f * 4];
    d[0] = v.x; d[1] = v.y; d[2] = v.z; d[3] = v.w;
  }
  __syncthreads();

  int q = t & 7;     // c-chunk of 16
  int pl = t >> 3;   // 0..31 pixel
  int cs = q * 16;
  u16x8 pk0, pk1;
#pragma unroll
  for (int j = 0; j < 8; ++j)
    pk0[j] = (unsigned short)f2bf(lds[(cs + j) * 33 + pl]);
#pragma unroll
  for (int j = 0; j < 8; ++j)
    pk1[j] = (unsigned short)f2bf(lds[(cs + 8 + j) * 33 + pl]);
  char* dst = (char*)two_t + ((size_t)((size_t)b * HWSZ + P0 + pl) * CC + cs) * 2;
  *(u16x8*)dst = pk0;
  *(u16x8*)(dst + 16) = pk1;
}

// ---------------- Kernel 1 (fast): gather from two_t [p][c] bf16 -----------
// One block per 64-px segment (no per-thread loop): 3584 blocks x 1024 thr,
// ~14 blocks/CU queue depth + 32 waves/CU hide the flow->gather chain.
// 16-lane group = one pixel, lane&15 = 16B channel chunk: all reads and the
// store are 256B-dense per group.
__global__ __launch_bounds__(1024) void warp_fast(
    const __hip_bfloat16* __restrict__ two_t, const float* __restrict__ flow,
    __hip_bfloat16* __restrict__ wt) {
  int bid = blockIdx.x;                    // 3584 = 8 * 448
  int wg = (bid & 7) * 448 + (bid >> 3);   // XCD-chunked, bijective
  int b = wg / 1792;
  int rem = wg - b * 1792;
  int y = rem / 7;
  int seg = rem - y * 7;
  int pg = threadIdx.x >> 4;  // 0..63 pixel group
  int cw = threadIdx.x & 15;  // 16B channel chunk
  int x = seg * 64 + pg;

  float fx = flow[(size_t)(b * 2 + 0) * HWSZ + y * WW + x] * 2.5f;
  float fy = flow[(size_t)(b * 2 + 1) * HWSZ + y * WW + x] * 2.5f;
  float px = (float)x + fx;
  float py = (float)y + fy;
  float x0f = floorf(px), y0f = floorf(py);
  int x0 = (int)x0f, y0 = (int)y0f;
  int x1 = x0 + 1, y1 = y0 + 1;
  float wx1 = px - x0f, wx0 = 1.0f - wx1;
  float wy1 = py - y0f, wy0 = 1.0f - wy1;
  bool vx0 = (x0 >= 0) && (x0 < WW);
  bool vx1 = (x1 >= 0) && (x1 < WW);
  bool vy0 = (y0 >= 0) && (y0 < HH);
  bool vy1 = (y1 >= 0) && (y1 < HH);
  float w00 = (vx0 && vy0) ? wx0 * wy0 : 0.0f;
  float w01 = (vx1 && vy0) ? wx1 * wy0 : 0.0f;
  float w10 = (vx0 && vy1) ? wx0 * wy1 : 0.0f;
  float w11 = (vx1 && vy1) ? wx1 * wy1 : 0.0f;
  int cx0 = min(max(x0, 0), WW - 1);
  int cx1 = min(max(x1, 0), WW - 1);
  int cy0 = min(max(y0, 0), HH - 1);
  int cy1 = min(max(y1, 0), HH - 1);

  const char* tb = (const char*)two_t + (size_t)b * HWSZ * (CC * 2);
  u16x8 a = *(const u16x8*)(tb + ((size_t)cy0 * WW + cx0) * 256 + cw * 16);
  u16x8 bb_ = *(const u16x8*)(tb + ((size_t)cy0 * WW + cx1) * 256 + cw * 16);
  u16x8 c = *(const u16x8*)(tb + ((size_t)cy1 * WW + cx0) * 256 + cw * 16);
  u16x8 d = *(const u16x8*)(tb + ((size_t)cy1 * WW + cx1) * 256 + cw * 16);

  u16x8 pk;
#pragma unroll
  for (int e = 0; e < 8; ++e) {
    float v = w00 * bf2f((unsigned short)a[e]) +
              w01 * bf2f((unsigned short)bb_[e]) +
              w10 * bf2f((unsigned short)c[e]) +
              w11 * bf2f((unsigned short)d[e]);
    pk[e] = (unsigned short)f2bf(v);
  }
  *(u16x8*)((char*)wt + ((size_t)(b * HH + y) * PW + x + 4) * (CC * 2) +
            cw * 16) = pk;
}

// ---------------- Kernel 1 (fallback): gather f32 planes directly -----------
__global__ __launch_bounds__(256) void warp_fallback(
    const float* __restrict__ two, const float* __restrict__ flow,
    __hip_bfloat16* __restrict__ wt) {
  int idx = blockIdx.x * 256 + threadIdx.x;
  if (idx >= BB * HWSZ) return;
  int x = idx % WW;
  int y = (idx / WW) % HH;
  int b = idx / HWSZ;

  float fx = flow[(b * 2 + 0) * HWSZ + y * WW + x] * 2.5f;
  float fy = flow[(b * 2 + 1) * HWSZ + y * WW + x] * 2.5f;
  float px = (float)x + fx;
  float py = (float)y + fy;
  float x0f = floorf(px), y0f = floorf(py);
  int x0 = (int)x0f, y0 = (int)y0f;
  int x1 = x0 + 1, y1 = y0 + 1;
  float wx1 = px - x0f, wx0 = 1.0f - wx1;
  float wy1 = py - y0f, wy0 = 1.0f - wy1;
  bool vx0 = (x0 >= 0) && (x0 < WW);
  bool vx1 = (x1 >= 0) && (x1 < WW);
  bool vy0 = (y0 >= 0) && (y0 < HH);
  bool vy1 = (y1 >= 0) && (y1 < HH);
  float w00 = (vx0 && vy0) ? wx0 * wy0 : 0.0f;
  float w01 = (vx1 && vy0) ? wx1 * wy0 : 0.0f;
  float w10 = (vx0 && vy1) ? wx0 * wy1 : 0.0f;
  float w11 = (vx1 && vy1) ? wx1 * wy1 : 0.0f;
  int cx0 = min(max(x0, 0), WW - 1);
  int cx1 = min(max(x1, 0), WW - 1);
  int cy0 = min(max(y0, 0), HH - 1);
  int cy1 = min(max(y1, 0), HH - 1);
  int o00 = cy0 * WW + cx0;
  int o01 = cy0 * WW + cx1;
  int o10 = cy1 * WW + cx0;
  int o11 = cy1 * WW + cx1;

  const float* p = two + (size_t)b * CC * HWSZ;
  char* wo = (char*)wt + ((size_t)((size_t)(b * HH + y) * PW) + x + 4) * CC * 2;
#pragma unroll 4
  for (int j = 0; j < 16; ++j) {
    u16x8 pk;
#pragma unroll
    for (int jj = 0; jj < 8; ++jj) {
      int c = j * 8 + jj;
      const float* pc = p + (size_t)c * HWSZ;
      float v = w00 * pc[o00] + w01 * pc[o01] + w10 * pc[o10] + w11 * pc[o11];
      pk[jj] = (unsigned short)f2bf(v);
    }
    *(u16x8*)(wo + j * 16) = pk;
  }
}

// ---------------- Kernel 2: correlation via MFMA (R14, unchanged) -----------
#define YTB 8
#define NROWS 14               // YTB + 6
#define NPOS 22
#define ROWCH (NPOS * 16)      // 352 16B-chunks per row
#define CHUNKS (NROWS * ROWCH) // 4928 chunks = 78,848 B

__global__ __launch_bounds__(512, 4) void corr_kernel(
    const float* __restrict__ one, const __hip_bfloat16* __restrict__ wt,
    float* __restrict__ out) {
  __shared__ uint4 ldsb[CHUNKS];

  int bid = blockIdx.x;                    // 1792 = 8 * 224
  int wg = (bid & 7) * 224 + (bid >> 3);   // XCD-chunked, bijective
  int b = wg / 896;
  int rem = wg - b * 896;
  int xt = rem >> 5;   // 0..27
  int yt = rem & 31;   // 0..31
  int ybase = yt * YTB;
  int X0 = xt * 16;
  int tid = threadIdx.x;
  int w = tid >> 6;   // wave 0..7
  int l = tid & 63;
  int lp = l & 15;
  int lg = l >> 4;
  int y = ybase + w;

  const char* wbase =
      (const char*)wt + (((size_t)(b * HH)) * PW + X0 + 1) * (CC * 2);
  bool interior = (ybase >= 3) && (ybase + NROWS - 3 <= HH);  // rows all valid

  if (interior) {
#pragma unroll
    for (int k = 0; k < 10; ++k) {
      int ci = tid + k * 512;
      if (k < 9 || tid < (CHUNKS - 9 * 512)) {
        int row = ci / ROWCH;
        int r2 = ci - row * ROWCH;
        int p = r2 >> 4;
        int cw = r2 & 15;
        int cwS = cw ^ (p & 15);  // pre-swizzled SOURCE (4-bit), linear DEST
        int yy = ybase - 3 + row;
        const char* g = wbase + (size_t)yy * (PW * CC * 2) + p * 256 + cwS * 16;
        int wave_ci0 = k * 512 + (tid & ~63);  // wave-uniform LDS base chunk
        gload_lds16(g, (char*)ldsb + (size_t)wave_ci0 * 16);
      }
    }
  } else {
#pragma unroll
    for (int k = 0; k < 10; ++k) {
      int ci = tid + k * 512;
      if (ci < CHUNKS) {
        int row = ci / ROWCH;
        int r2 = ci - row * ROWCH;
        int p = r2 >> 4;
        int cw = r2 & 15;
        int yy = ybase - 3 + row;
        uint4 v = {0, 0, 0, 0};
        if (yy >= 0 && yy < HH)
          v = *(const uint4*)(wbase + (size_t)yy * (PW * CC * 2) + p * 256 +
                              cw * 16);
        *(uint4*)((char*)ldsb + ((ci * 16) ^ ((p & 15) << 4))) = v;
      }
    }
  }

  const float* Abase = one + ((size_t)(b * CC) * HH + y) * WW + X0 + lp;
  bf16x8 afr[4];
#pragma unroll
  for (int t = 0; t < 4; ++t)
#pragma unroll
    for (int j = 0; j < 8; ++j)
      afr[t][j] = f2bf(Abase[(size_t)(t * 32 + lg * 8 + j) * HWSZ]);

  __syncthreads();  // drains vmcnt (gload_lds) / lgkmcnt (edge ds_write)

  int p1 = (lp + 16 < 21) ? (lp + 16) : 21;
  int cosw0[4], cosw1[4];
#pragma unroll
  for (int t = 0; t < 4; ++t) {
    int co = t * 64 + lg * 16;
    cosw0[t] = co ^ ((lp & 15) << 4);
    cosw1[t] = co ^ ((p1 & 15) << 4);
  }

  f32x4 acc[7][2] = {};
#pragma unroll
  for (int dj = 0; dj < 7; ++dj) {
    int rl = w + dj;  // LDS row for yy = y + dj - 3
    int b0 = (rl * NPOS + lp) << 8;
    int b1 = (rl * NPOS + p1) << 8;
#pragma unroll
    for (int t = 0; t < 4; ++t) {
      bf16x8 v0 = *(const bf16x8*)((const char*)ldsb + (b0 + cosw0[t]));
      bf16x8 v1 = *(const bf16x8*)((const char*)ldsb + (b1 + cosw1[t]));
      acc[dj][0] = __builtin_amdgcn_mfma_f32_16x16x32_bf16(afr[t], v0,
                                                           acc[dj][0], 0, 0, 0);
      acc[dj][1] = __builtin_amdgcn_mfma_f32_16x16x32_bf16(afr[t], v1,
                                                           acc[dj][1], 0, 0, 0);
    }
  }

  // Epilogue: LDS transpose -> dense stores.
  __syncthreads();  // all ds_reads of ldsb done; safe to reuse as scratch
  float* sc = (float*)ldsb;  // [49][8][16] f32, col-swizzled by +k (mod 16)
#pragma unroll
  for (int dj = 0; dj < 7; ++dj) {
#pragma unroll
    for (int nt = 0; nt < 2; ++nt) {
      int post = lp + 16 * nt;
#pragma unroll
      for (int r = 0; r < 4; ++r) {
        int xlc = 4 * lg + r;
        int di = post - xlc;
        if (di >= 0 && di <= 6) {
          int k = dj * 7 + di;
          sc[k * 128 + w * 16 + ((xlc + k) & 15)] = acc[dj][nt][r];
        }
      }
    }
  }
  __syncthreads();

  float* ob = out + (size_t)(b * KK) * HWSZ + (size_t)ybase * WW + X0;
#pragma unroll
  for (int i = 0; i < 13; ++i) {
    int e = tid + i * 512;
    if (e < KK * 128) {
      int k = e >> 7;
      int yr = (e >> 4) & 7;
      int px = e & 15;
      float v = sc[k * 128 + yr * 16 + ((px + k) & 15)] * (1.0f / 128.0f);
      v = (v > 0.0f) ? v : 0.1f * v;
      ob[(size_t)k * HWSZ + yr * WW + px] = v;
    }
  }
}

// ---------------- launch ----------------------------------------------------
extern "C" void kernel_launch(void* const* d_in, const int* in_sizes, int n_in,
                              void* d_out, int out_size, void* d_ws,
                              size_t ws_size, hipStream_t stream) {
  const float* tenOne = (const float*)d_in[0];
  const float* tenTwo = (const float*)d_in[1];
  const float* tenFlow = (const float*)d_in[2];

  __hip_bfloat16* wt = (__hip_bfloat16*)d_ws;

  if (ws_size >= WS_NEED) {
    __hip_bfloat16* two_t = (__hip_bfloat16*)((char*)d_ws + WT_BYTES);
    transpose_kernel<<<BB * (HWSZ / 32), 256, 0, stream>>>(tenTwo, two_t, wt);
    warp_fast<<<3584, 1024, 0, stream>>>(two_t, tenFlow, wt);
  } else {
    border_kernel<<<256, 256, 0, stream>>>(wt);
    int blocks = (BB * HWSZ + 255) / 256;
    warp_fallback<<<blocks, 256, 0, stream>>>(tenTwo, tenFlow, wt);
  }
  corr_kernel<<<1792, 512, 0, stream>>>(tenOne, wt, (float*)d_out);
}